// Round 11
// baseline (220.637 us; speedup 1.0000x reference)
//
#include <hip/hip_runtime.h>
#include <hip/hip_bf16.h>
#include <cfloat>

// VQ-VAE vector quantizer.  N=262144 rows x D=100, K=512 codes.
// out[0..N*D-1] = quantized (fp32-exact gather); out[N*D]=mse; out[N*D+1]=0.25*mse.
//
// R16: R14 (best, 86us) with the main loop on mfma_f32_32x32x16_bf16.
//  Post-mortem R15: fp8 halved the LDS-read pipe and REGRESSED (+5us) -- the
//  serialized resource is wave ISSUE + operand flow, not the LDS pipe
//  (calibration: R14 VALU cut -> 1:1 time; R15 LDS cut -> 0, minus repack cost).
//  R16 cuts issued instructions: 32x32x16 MFMA does 4x work/instruction.
//  Per round (2 chunks): 64->28 MFMA, 16->14 ds_read, fold kept at 96 by
//  pairing chunks into one max3; staging/epilogue structure unchanged.
//  Layouts: C/D 32x32 HW-verified (m74/m101): col=lane&31,
//  row=(reg&3)+8*(reg>>2)+4*(lane>>5).  A/B k-map: k=(lane>>5)*8+j per
//  16-K slice -- same rule our 16x16x32 granules validated for 10 rounds.
//  Tripwires: absmax <= 0.00390625 (layout!); WRITE exactly 102432 (spill,
//  VGPR est ~210 under (256,2) cap 256); conflicts 0 (lane-linear LDS).
//  Falsifier: pass but dur >= 84us -> instruction lever exhausted.
//
// ws: ws_f[0] = loss accum; ws_f[16..528) = e2[k] (fp32, reference);
//     bytes [4096..4096+114688): bf16 cb32; chunk c (7168 B) granule16 layout:
//     granule g = (s*2+hi)*32 + col  holds code (c*32+col),
//     elem j: k = s*16 + hi*8 + j  (s=0..6); k==100 -> bf16(-e2/2); k>100 -> 0.

#define N_ROWS (64 * 64 * 64)
#define D 100
#define KCODES 512
#define CB_OFF 4096
#define E2_OFF 16

typedef __attribute__((ext_vector_type(8))) short short8;
typedef __attribute__((ext_vector_type(16))) float f32x16;

__device__ __forceinline__ unsigned short f2bf(float f) {
    union { float f; unsigned u; } v; v.f = f;
    unsigned r = v.u + 0x7FFF + ((v.u >> 16) & 1);   // RNE
    return (unsigned short)(r >> 16);
}
__device__ __forceinline__ unsigned pk2(float a, float b) {   // packed bf16 cvt (RNE)
    union { __hip_bfloat162 h; unsigned u; } c;
    c.h = __float22bfloat162_rn(make_float2(a, b));
    return c.u;
}
__device__ __forceinline__ short8 pack8(const float4& a, const float4& b) {
    union { unsigned u[4]; short8 v; } r;
    r.u[0] = pk2(a.x, a.y); r.u[1] = pk2(a.z, a.w);
    r.u[2] = pk2(b.x, b.y); r.u[3] = pk2(b.z, b.w);
    return r.v;
}
__device__ __forceinline__ unsigned f2u(float f) {
    union { float f; unsigned u; } v; v.f = f; return v.u;
}
__device__ __forceinline__ float u2f(unsigned u) {
    union { unsigned u; float f; } v; v.u = u; return v.f;
}

// ---- init: one wave per code; 32-col granule layout ----
__global__ __launch_bounds__(64) void vq_init(const float* __restrict__ emb,
                                              float* __restrict__ ws) {
    const int code = blockIdx.x, l = threadIdx.x;
    const float* e = emb + code * D;
    if (code == 0 && l == 0) ws[0] = 0.0f;
    float a = e[l];
    float b = (l < D - 64) ? e[64 + l] : 0.0f;
    float p = fmaf(a, a, b * b);
#pragma unroll
    for (int off = 32; off; off >>= 1) p += __shfl_xor(p, off);   // all lanes: e2
    if (l == 0) ws[E2_OFF + code] = p;

    // cb32 granules: 14 per code (s=0..6, hi=0..1), lanes 0..13
    if (l < 14) {
        const int s = l >> 1, hi = l & 1;
        short8 v;
#pragma unroll
        for (int j = 0; j < 8; ++j) {
            int k = s * 16 + hi * 8 + j;
            float val = (k < D) ? e[k] : (k == D ? -0.5f * p : 0.0f);
            v[j] = (short)f2bf(val);
        }
        const int chunk = code >> 5, col = code & 31;
        short8* cb = (short8*)((char*)ws + CB_OFF);
        cb[chunk * 448 + (s * 2 + hi) * 32 + col] = v;
    }
}

// ---- main: 4 waves/block, 64 rows/wave (2x32), 32x32x16 MFMA ----
__global__ __launch_bounds__(256, 2) void vq_main(const float* __restrict__ x,
                                                  const float* __restrict__ emb,
                                                  float* __restrict__ ws,
                                                  float* __restrict__ out) {
    __shared__ uint4  bbuf[2][896];   // 2 x 14 KB: two cb32 chunks per buffer
    __shared__ int    widx[256];
    __shared__ float  wsum[4];

    const int tid = threadIdx.x, wave = tid >> 6, lane = tid & 63;
    const int hi = lane >> 5, col = lane & 31;
    const long brow = (long)blockIdx.x * 256;
    const long wrow = brow + wave * 64;

    // ---- A: 26 independent scattered loads (row = col, k-half = hi) ----
    float4 av[2][13];
#pragma unroll
    for (int t = 0; t < 2; ++t) {
        const float* xr = x + (wrow + t * 32 + col) * D + hi * 8;
#pragma unroll
        for (int s = 0; s < 6; ++s) {
            av[t][2 * s]     = *(const float4*)(xr + s * 16);
            av[t][2 * s + 1] = *(const float4*)(xr + s * 16 + 4);
        }
        av[t][12] = *(const float4*)(x + (wrow + t * 32 + col) * D + 96); // both hi
    }

    // ---- staging round 0 (chunks 0,1 = 896 granules; tid<128 take a 4th) ----
    const uint4* __restrict__ cbg = (const uint4*)((const char*)ws + CB_OFF);
    uint4 st0 = cbg[tid];
    uint4 st1 = cbg[256 + tid];
    uint4 st2 = cbg[512 + tid];
    uint4 st3;
    if (tid < 128) st3 = cbg[768 + tid];

    // ---- convert A -> fragments + fp32 norms; k=100 carries 1.0 (hi 0) ----
    short8 A8[2][7];
    float  xnorm[2];
#pragma unroll
    for (int t = 0; t < 2; ++t) {
        float4 z = av[t][12];
        if (hi != 0) z = make_float4(0.f, 0.f, 0.f, 0.f);   // tail only in hi 0
        float nrm = 0.f;
#pragma unroll
        for (int i = 0; i < 12; ++i) {
            float4 f = av[t][i];
            nrm = fmaf(f.x, f.x, nrm); nrm = fmaf(f.y, f.y, nrm);
            nrm = fmaf(f.z, f.z, nrm); nrm = fmaf(f.w, f.w, nrm);
        }
        nrm = fmaf(z.x, z.x, nrm); nrm = fmaf(z.y, z.y, nrm);
        nrm = fmaf(z.z, z.z, nrm); nrm = fmaf(z.w, z.w, nrm);
#pragma unroll
        for (int s = 0; s < 6; ++s) A8[t][s] = pack8(av[t][2 * s], av[t][2 * s + 1]);
        A8[t][6] = pack8(z, make_float4(hi == 0 ? 1.f : 0.f, 0.f, 0.f, 0.f));
        nrm += __shfl_xor(nrm, 32);          // pair (col,hi) + (col,hi^1) = full row
        xnorm[t] = nrm;
    }

    bbuf[0][tid]       = st0;
    bbuf[0][256 + tid] = st1;
    bbuf[0][512 + tid] = st2;
    if (tid < 128) bbuf[0][768 + tid] = st3;
    __syncthreads();

    // packed running max: acc with 9 LSBs = 511-code (argmax acc == argmin score)
    float run[2][16];
#pragma unroll
    for (int t = 0; t < 2; ++t)
#pragma unroll
        for (int r = 0; r < 16; ++r) run[t][r] = -FLT_MAX;

    const int ibase = 31 - col;

#pragma unroll 1
    for (int j = 0; j < 8; ++j) {
        const int p = j & 1;
        uint4 n0, n1, n2, n3;
        if (j < 7) {                      // prefetch next 2 chunks into regs
            const int gb = (j + 1) * 896;
            n0 = cbg[gb + tid];
            n1 = cbg[gb + 256 + tid];
            n2 = cbg[gb + 512 + tid];
            if (tid < 128) n3 = cbg[gb + 768 + tid];
        }

        f32x16 acc[2][2];                 // [cc][t]
#pragma unroll
        for (int cc = 0; cc < 2; ++cc) {
            // B fragments: 7 lane-linear ds_read_b128, conflict-free
            const short8* __restrict__ bl8 = (const short8*)&bbuf[p][cc * 448];
            short8 B[7];
#pragma unroll
            for (int s = 0; s < 7; ++s) B[s] = bl8[(s * 2 + hi) * 32 + col];

            acc[cc][0] = (f32x16)(0.f);
            acc[cc][1] = (f32x16)(0.f);
#pragma unroll
            for (int s = 0; s < 7; ++s)
#pragma unroll
                for (int t = 0; t < 2; ++t)
                    acc[cc][t] = __builtin_amdgcn_mfma_f32_32x32x16_bf16(A8[t][s], B[s], acc[cc][t], 0, 0, 0);
        }

        // fold both chunks: pack (511-code) into 9 LSBs, one max3 per (t,r)
        const int ib0 = (15 - 2 * j) * 32 + ibase;
        const int ib1 = ib0 - 32;
#pragma unroll
        for (int t = 0; t < 2; ++t)
#pragma unroll
            for (int r = 0; r < 16; ++r) {
                float p0 = u2f((f2u(acc[0][t][r]) & ~511u) | (unsigned)ib0);
                float p1 = u2f((f2u(acc[1][t][r]) & ~511u) | (unsigned)ib1);
                run[t][r] = fmaxf(run[t][r], fmaxf(p0, p1));
            }

        if (j < 7) {
            bbuf[p ^ 1][tid]       = n0;
            bbuf[p ^ 1][256 + tid] = n1;
            bbuf[p ^ 1][512 + tid] = n2;
            if (tid < 128) bbuf[p ^ 1][768 + tid] = n3;
        }
        __syncthreads();
    }

    // ---- per-row argmax across 32 cols: 5-step float max-reduce (in-half) ----
    float lsum = 0.0f;
#pragma unroll
    for (int t = 0; t < 2; ++t)
#pragma unroll
        for (int r = 0; r < 16; ++r) {
            float s = run[t][r];
#pragma unroll
            for (int off = 16; off >= 1; off >>= 1)
                s = fmaxf(s, __shfl_xor(s, off));
            const int rowl = (r & 3) + 8 * (r >> 2) + 4 * hi;   // C row (m74/m101)
            if (col == rowl) {                                  // 1 writer per half
                unsigned u = f2u(s);
                widx[wave * 64 + t * 32 + rowl] = 511 - (int)(u & 511u);
                lsum += fmaf(-2.0f, s, xnorm[t]);   // ||x||^2 - 2*(<x,e> - e2/2)
            }
        }
#pragma unroll
    for (int off = 32; off >= 1; off >>= 1) lsum += __shfl_xor(lsum, off);
    if (lane == 0) wsum[wave] = lsum;
    __syncthreads();                                   // wsum + widx visible
    if (tid == 0) atomicAdd(ws, wsum[0] + wsum[1] + wsum[2] + wsum[3]);

    // ---- coalesced epilogue: 6400 float4 = 256 rows x 25, batched 5-deep ----
    const float4* __restrict__ ef = (const float4*)emb;   // 25 float4 per row, exact
    float4* __restrict__ og = (float4*)(out + brow * D);
#pragma unroll
    for (int i = 0; i < 25; i += 5) {
        float4 q[5];
        int    gi[5];
#pragma unroll
        for (int u = 0; u < 5; ++u) {
            int g = (i + u) * 256 + tid;
            int row = g / 25;                 // const-divisor magic div
            int c4  = g - row * 25;
            gi[u] = g;
            q[u]  = ef[(long)widx[row] * 25 + c4];
        }
#pragma unroll
        for (int u = 0; u < 5; ++u) og[gi[u]] = q[u];
    }
}

// ---- finalize ----
__global__ void vq_final(const float* __restrict__ ws, float* __restrict__ out) {
    float mse = ws[0] / (float)((long)N_ROWS * D);
    out[(long)N_ROWS * D]     = mse;
    out[(long)N_ROWS * D + 1] = 0.25f * mse;
}

extern "C" void kernel_launch(void* const* d_in, const int* in_sizes, int n_in,
                              void* d_out, int out_size, void* d_ws, size_t ws_size,
                              hipStream_t stream) {
    const float* x   = (const float*)d_in[0];
    const float* emb = (const float*)d_in[1];
    float* out = (float*)d_out;
    float* ws  = (float*)d_ws;

    vq_init<<<KCODES, 64, 0, stream>>>(emb, ws);
    vq_main<<<N_ROWS / 256, 256, 0, stream>>>(x, emb, ws, out);
    vq_final<<<1, 1, 0, stream>>>(ws, out);
}

// Round 12
// 219.500 us; speedup vs baseline: 1.0052x; 1.0052x over previous
//
#include <hip/hip_runtime.h>
#include <hip/hip_bf16.h>
#include <cfloat>

// VQ-VAE vector quantizer.  N=262144 rows x D=100, K=512 codes.
// out[0..N*D-1] = quantized (fp32-exact gather); out[N*D]=mse; out[N*D+1]=0.25*mse.
//
// R17: R16 with the MFMA block re-ordered for 4 interleaved chains.
//  Post-mortem R16 (91us vs R14 86us): issue counts fell (VALUBusy 22->15,
//  MfmaUtil 15.6->12.6) yet time rose => critical path grew.  Cause: cc-inner
//  ordering left only 2 dependent-MFMA chains (t=0,1) per cc block; spacing
//  2 x 8cyc = 16cyc < 32x32-MFMA dependent latency (~32-40cyc, 16-reg result)
//  => ~20cyc stall per MFMA pair.  R14's s-inner order had 8 chains (40cyc
//  spacing) and never stalled.  Law: this kernel responds to per-wave
//  dependent path + issued work; not pipe load, not occupancy.
//  R17 = R16 with ONE change: hoist B loads for both chunks (14 ds_read,
//  same count), then  for s: for cc: for t: mfma  -> 4 chains, 32cyc spacing.
//  Everything else (granule layout, fold, staging, epilogue) = R16.
//  Tripwires: WRITE exactly 102432 (VGPR est ~230/256 -- spill shows here);
//  conflicts 0; absmax <= 0.00390625.
//  Falsifier: dur ~= 91us -> chain theory wrong -> revert to R14.
//
// ws: ws_f[0] = loss accum; ws_f[16..528) = e2[k] (fp32, reference);
//     bytes [4096..4096+114688): bf16 cb32; chunk c (7168 B) granule16 layout:
//     granule g = (s*2+hi)*32 + col  holds code (c*32+col),
//     elem j: k = s*16 + hi*8 + j  (s=0..6); k==100 -> bf16(-e2/2); k>100 -> 0.

#define N_ROWS (64 * 64 * 64)
#define D 100
#define KCODES 512
#define CB_OFF 4096
#define E2_OFF 16

typedef __attribute__((ext_vector_type(8))) short short8;
typedef __attribute__((ext_vector_type(16))) float f32x16;

__device__ __forceinline__ unsigned short f2bf(float f) {
    union { float f; unsigned u; } v; v.f = f;
    unsigned r = v.u + 0x7FFF + ((v.u >> 16) & 1);   // RNE
    return (unsigned short)(r >> 16);
}
__device__ __forceinline__ unsigned pk2(float a, float b) {   // packed bf16 cvt (RNE)
    union { __hip_bfloat162 h; unsigned u; } c;
    c.h = __float22bfloat162_rn(make_float2(a, b));
    return c.u;
}
__device__ __forceinline__ short8 pack8(const float4& a, const float4& b) {
    union { unsigned u[4]; short8 v; } r;
    r.u[0] = pk2(a.x, a.y); r.u[1] = pk2(a.z, a.w);
    r.u[2] = pk2(b.x, b.y); r.u[3] = pk2(b.z, b.w);
    return r.v;
}
__device__ __forceinline__ unsigned f2u(float f) {
    union { float f; unsigned u; } v; v.f = f; return v.u;
}
__device__ __forceinline__ float u2f(unsigned u) {
    union { unsigned u; float f; } v; v.u = u; return v.f;
}

// ---- init: one wave per code; 32-col granule layout ----
__global__ __launch_bounds__(64) void vq_init(const float* __restrict__ emb,
                                              float* __restrict__ ws) {
    const int code = blockIdx.x, l = threadIdx.x;
    const float* e = emb + code * D;
    if (code == 0 && l == 0) ws[0] = 0.0f;
    float a = e[l];
    float b = (l < D - 64) ? e[64 + l] : 0.0f;
    float p = fmaf(a, a, b * b);
#pragma unroll
    for (int off = 32; off; off >>= 1) p += __shfl_xor(p, off);   // all lanes: e2
    if (l == 0) ws[E2_OFF + code] = p;

    // cb32 granules: 14 per code (s=0..6, hi=0..1), lanes 0..13
    if (l < 14) {
        const int s = l >> 1, hi = l & 1;
        short8 v;
#pragma unroll
        for (int j = 0; j < 8; ++j) {
            int k = s * 16 + hi * 8 + j;
            float val = (k < D) ? e[k] : (k == D ? -0.5f * p : 0.0f);
            v[j] = (short)f2bf(val);
        }
        const int chunk = code >> 5, col = code & 31;
        short8* cb = (short8*)((char*)ws + CB_OFF);
        cb[chunk * 448 + (s * 2 + hi) * 32 + col] = v;
    }
}

// ---- main: 4 waves/block, 64 rows/wave (2x32), 32x32x16 MFMA, 4 chains ----
__global__ __launch_bounds__(256, 2) void vq_main(const float* __restrict__ x,
                                                  const float* __restrict__ emb,
                                                  float* __restrict__ ws,
                                                  float* __restrict__ out) {
    __shared__ uint4  bbuf[2][896];   // 2 x 14 KB: two cb32 chunks per buffer
    __shared__ int    widx[256];
    __shared__ float  wsum[4];

    const int tid = threadIdx.x, wave = tid >> 6, lane = tid & 63;
    const int hi = lane >> 5, col = lane & 31;
    const long brow = (long)blockIdx.x * 256;
    const long wrow = brow + wave * 64;

    // ---- A: 26 independent scattered loads (row = col, k-half = hi) ----
    float4 av[2][13];
#pragma unroll
    for (int t = 0; t < 2; ++t) {
        const float* xr = x + (wrow + t * 32 + col) * D + hi * 8;
#pragma unroll
        for (int s = 0; s < 6; ++s) {
            av[t][2 * s]     = *(const float4*)(xr + s * 16);
            av[t][2 * s + 1] = *(const float4*)(xr + s * 16 + 4);
        }
        av[t][12] = *(const float4*)(x + (wrow + t * 32 + col) * D + 96); // both hi
    }

    // ---- staging round 0 (chunks 0,1 = 896 granules; tid<128 take a 4th) ----
    const uint4* __restrict__ cbg = (const uint4*)((const char*)ws + CB_OFF);
    uint4 st0 = cbg[tid];
    uint4 st1 = cbg[256 + tid];
    uint4 st2 = cbg[512 + tid];
    uint4 st3;
    if (tid < 128) st3 = cbg[768 + tid];

    // ---- convert A -> fragments + fp32 norms; k=100 carries 1.0 (hi 0) ----
    short8 A8[2][7];
    float  xnorm[2];
#pragma unroll
    for (int t = 0; t < 2; ++t) {
        float4 z = av[t][12];
        if (hi != 0) z = make_float4(0.f, 0.f, 0.f, 0.f);   // tail only in hi 0
        float nrm = 0.f;
#pragma unroll
        for (int i = 0; i < 12; ++i) {
            float4 f = av[t][i];
            nrm = fmaf(f.x, f.x, nrm); nrm = fmaf(f.y, f.y, nrm);
            nrm = fmaf(f.z, f.z, nrm); nrm = fmaf(f.w, f.w, nrm);
        }
        nrm = fmaf(z.x, z.x, nrm); nrm = fmaf(z.y, z.y, nrm);
        nrm = fmaf(z.z, z.z, nrm); nrm = fmaf(z.w, z.w, nrm);
#pragma unroll
        for (int s = 0; s < 6; ++s) A8[t][s] = pack8(av[t][2 * s], av[t][2 * s + 1]);
        A8[t][6] = pack8(z, make_float4(hi == 0 ? 1.f : 0.f, 0.f, 0.f, 0.f));
        nrm += __shfl_xor(nrm, 32);          // pair (col,hi) + (col,hi^1) = full row
        xnorm[t] = nrm;
    }

    bbuf[0][tid]       = st0;
    bbuf[0][256 + tid] = st1;
    bbuf[0][512 + tid] = st2;
    if (tid < 128) bbuf[0][768 + tid] = st3;
    __syncthreads();

    // packed running max: acc with 9 LSBs = 511-code (argmax acc == argmin score)
    float run[2][16];
#pragma unroll
    for (int t = 0; t < 2; ++t)
#pragma unroll
        for (int r = 0; r < 16; ++r) run[t][r] = -FLT_MAX;

    const int ibase = 31 - col;

#pragma unroll 1
    for (int j = 0; j < 8; ++j) {
        const int p = j & 1;
        uint4 n0, n1, n2, n3;
        if (j < 7) {                      // prefetch next 2 chunks into regs
            const int gb = (j + 1) * 896;
            n0 = cbg[gb + tid];
            n1 = cbg[gb + 256 + tid];
            n2 = cbg[gb + 512 + tid];
            if (tid < 128) n3 = cbg[gb + 768 + tid];
        }

        // B fragments for BOTH chunks: 14 lane-linear ds_read_b128, conflict-free
        short8 B[2][7];
#pragma unroll
        for (int cc = 0; cc < 2; ++cc) {
            const short8* __restrict__ bl8 = (const short8*)&bbuf[p][cc * 448];
#pragma unroll
            for (int s = 0; s < 7; ++s) B[cc][s] = bl8[(s * 2 + hi) * 32 + col];
        }

        // 4 interleaved accumulator chains (cc x t): dep spacing = 4 MFMAs
        f32x16 acc[2][2];
        acc[0][0] = (f32x16)(0.f); acc[0][1] = (f32x16)(0.f);
        acc[1][0] = (f32x16)(0.f); acc[1][1] = (f32x16)(0.f);
#pragma unroll
        for (int s = 0; s < 7; ++s)
#pragma unroll
            for (int cc = 0; cc < 2; ++cc)
#pragma unroll
                for (int t = 0; t < 2; ++t)
                    acc[cc][t] = __builtin_amdgcn_mfma_f32_32x32x16_bf16(A8[t][s], B[cc][s], acc[cc][t], 0, 0, 0);

        // fold both chunks: pack (511-code) into 9 LSBs, one max3 per (t,r)
        const int ib0 = (15 - 2 * j) * 32 + ibase;
        const int ib1 = ib0 - 32;
#pragma unroll
        for (int t = 0; t < 2; ++t)
#pragma unroll
            for (int r = 0; r < 16; ++r) {
                float p0 = u2f((f2u(acc[0][t][r]) & ~511u) | (unsigned)ib0);
                float p1 = u2f((f2u(acc[1][t][r]) & ~511u) | (unsigned)ib1);
                run[t][r] = fmaxf(run[t][r], fmaxf(p0, p1));
            }

        if (j < 7) {
            bbuf[p ^ 1][tid]       = n0;
            bbuf[p ^ 1][256 + tid] = n1;
            bbuf[p ^ 1][512 + tid] = n2;
            if (tid < 128) bbuf[p ^ 1][768 + tid] = n3;
        }
        __syncthreads();
    }

    // ---- per-row argmax across 32 cols: 5-step float max-reduce (in-half) ----
    float lsum = 0.0f;
#pragma unroll
    for (int t = 0; t < 2; ++t)
#pragma unroll
        for (int r = 0; r < 16; ++r) {
            float s = run[t][r];
#pragma unroll
            for (int off = 16; off >= 1; off >>= 1)
                s = fmaxf(s, __shfl_xor(s, off));
            const int rowl = (r & 3) + 8 * (r >> 2) + 4 * hi;   // C row (m74/m101)
            if (col == rowl) {                                  // 1 writer per half
                unsigned u = f2u(s);
                widx[wave * 64 + t * 32 + rowl] = 511 - (int)(u & 511u);
                lsum += fmaf(-2.0f, s, xnorm[t]);   // ||x||^2 - 2*(<x,e> - e2/2)
            }
        }
#pragma unroll
    for (int off = 32; off >= 1; off >>= 1) lsum += __shfl_xor(lsum, off);
    if (lane == 0) wsum[wave] = lsum;
    __syncthreads();                                   // wsum + widx visible
    if (tid == 0) atomicAdd(ws, wsum[0] + wsum[1] + wsum[2] + wsum[3]);

    // ---- coalesced epilogue: 6400 float4 = 256 rows x 25, batched 5-deep ----
    const float4* __restrict__ ef = (const float4*)emb;   // 25 float4 per row, exact
    float4* __restrict__ og = (float4*)(out + brow * D);
#pragma unroll
    for (int i = 0; i < 25; i += 5) {
        float4 q[5];
        int    gi[5];
#pragma unroll
        for (int u = 0; u < 5; ++u) {
            int g = (i + u) * 256 + tid;
            int row = g / 25;                 // const-divisor magic div
            int c4  = g - row * 25;
            gi[u] = g;
            q[u]  = ef[(long)widx[row] * 25 + c4];
        }
#pragma unroll
        for (int u = 0; u < 5; ++u) og[gi[u]] = q[u];
    }
}

// ---- finalize ----
__global__ void vq_final(const float* __restrict__ ws, float* __restrict__ out) {
    float mse = ws[0] / (float)((long)N_ROWS * D);
    out[(long)N_ROWS * D]     = mse;
    out[(long)N_ROWS * D + 1] = 0.25f * mse;
}

extern "C" void kernel_launch(void* const* d_in, const int* in_sizes, int n_in,
                              void* d_out, int out_size, void* d_ws, size_t ws_size,
                              hipStream_t stream) {
    const float* x   = (const float*)d_in[0];
    const float* emb = (const float*)d_in[1];
    float* out = (float*)d_out;
    float* ws  = (float*)d_ws;

    vq_init<<<KCODES, 64, 0, stream>>>(emb, ws);
    vq_main<<<N_ROWS / 256, 256, 0, stream>>>(x, emb, ws, out);
    vq_final<<<1, 1, 0, stream>>>(ws, out);
}